// Round 6
// baseline (597.006 us; speedup 1.0000x reference)
//
#include <hip/hip_runtime.h>
#include <stdint.h>

#define B_   16
#define L_   2048
#define D_   256
#define NROW (B_*L_)

#define EPAD 40    // Es row stride (shorts), 80 B (16B-aligned)
#define TPAD 66    // qkv transpose buffer row stride

typedef __attribute__((ext_vector_type(8)))  short s8v;   // 8 x bf16
typedef __attribute__((ext_vector_type(4)))  float f4v;   // 16x16 acc
typedef __attribute__((ext_vector_type(16))) float f16v;  // 32x32 acc

__device__ __forceinline__ unsigned short f2b(float f) {   // RNE f32->bf16
    unsigned u = __builtin_bit_cast(unsigned, f);
    return (unsigned short)((u + 0x7fffu + ((u >> 16) & 1u)) >> 16);
}

// async global->LDS, 16B/lane; LDS dest = wave-uniform base + lane*16
__device__ __forceinline__ void gl16(const void* g, void* l) {
    __builtin_amdgcn_global_load_lds(
        (const __attribute__((address_space(1))) unsigned int*)g,
        (__attribute__((address_space(3))) unsigned int*)l, 16, 0, 0);
}

// ---------------- K1: QKV projection, 3 balanced types ----------------
// grid (512 row-blocks, 3 types[Q,K,V]), block 256 (4 waves). Each block:
// stage its input tile once, loop 4 weight col-tiles (W stays L2-hot).
__global__ __launch_bounds__(256) void qkv_kernel(
    const float* __restrict__ x, const float* __restrict__ y,
    const float* __restrict__ Wq, const float* __restrict__ Wk, const float* __restrict__ Wv,
    unsigned short* __restrict__ Qb, unsigned short* __restrict__ Kb,
    unsigned short* __restrict__ Vt,
    float* __restrict__ qn, float* __restrict__ kn)
{
    __shared__ unsigned short Xs[64*256];    // 32 KB input tile (bf16)
    __shared__ unsigned short Ws[64*256];    // 32 KB weight tile (bf16)
    __shared__ unsigned short Ts[64*TPAD];   // V transpose buffer

    const int t    = threadIdx.x;
    const int r0   = blockIdx.x * 64;   // global row (flat b*L + pos)
    const int type = blockIdx.y;        // 0=Q 1=K 2=V

    const float* X = (type == 0) ? x : y;
    const float* W = (type == 0) ? Wq : (type == 1) ? Wk : Wv;

    // Stage X tile [64][256] fp32 -> bf16 LDS, 16B-chunk swizzled by row&15.
    #pragma unroll
    for (int p = 0; p < 16; ++p) {
        int idx  = p*256 + t;
        int row  = idx >> 6;
        int half = idx & 1;
        int blk  = (idx & 63) >> 1;
        int c4   = blk*8 + half*4;
        float4 vx = *(const float4*)(X + (size_t)(r0+row)*D_ + c4);
        uint2 px;
        px.x = (unsigned)f2b(vx.x) | ((unsigned)f2b(vx.y) << 16);
        px.y = (unsigned)f2b(vx.z) | ((unsigned)f2b(vx.w) << 16);
        *(uint2*)(Xs + row*256 + (blk ^ (row & 15))*8 + half*4) = px;
    }

    const int w = t >> 6, lane = t & 63, q16 = lane & 15, quad = lane >> 4;
    const int m0 = w * 16;

    float p4[4] = {0.f, 0.f, 0.f, 0.f};
    const f4v z4 = {0.f, 0.f, 0.f, 0.f};

    for (int ct = 0; ct < 4; ++ct) {
        const int e0 = ct * 64;
        __syncthreads();   // prev readers done (covers Xs stage on ct=0)
        #pragma unroll
        for (int p = 0; p < 16; ++p) {
            int idx  = p*256 + t;
            int row  = idx >> 6;
            int half = idx & 1;
            int blk  = (idx & 63) >> 1;
            int c4   = blk*8 + half*4;
            float4 vw = *(const float4*)(W + (size_t)(e0+row)*D_ + c4);
            uint2 pw;
            pw.x = (unsigned)f2b(vw.x) | ((unsigned)f2b(vw.y) << 16);
            pw.y = (unsigned)f2b(vw.z) | ((unsigned)f2b(vw.w) << 16);
            *(uint2*)(Ws + row*256 + (blk ^ (row & 15))*8 + half*4) = pw;
        }
        __syncthreads();

        f4v acc[4];
        #pragma unroll
        for (int n = 0; n < 4; ++n) acc[n] = z4;
        #pragma unroll
        for (int c = 0; c < 8; ++c) {
            s8v a = *(const s8v*)(Xs + (m0 + q16)*256 + (((c*4+quad) ^ q16)*8));
            #pragma unroll
            for (int n = 0; n < 4; ++n) {
                s8v bb = *(const s8v*)(Ws + (n*16 + q16)*256 + (((c*4+quad) ^ q16)*8));
                acc[n] = __builtin_amdgcn_mfma_f32_16x16x32_bf16(a, bb, acc[n], 0, 0, 0);
            }
        }

        if (type < 2) {
            unsigned short* Out = (type == 0) ? Qb : Kb;
            #pragma unroll
            for (int n = 0; n < 4; ++n)
                #pragma unroll
                for (int r = 0; r < 4; ++r) {
                    float v = acc[n][r];
                    p4[r] += v * v;
                    Out[(size_t)(r0 + m0 + quad*4 + r)*D_ + e0 + n*16 + q16] = f2b(v);
                }
        } else {
            // V: transpose via LDS, write Vt[b][d][k] coalesced
            #pragma unroll
            for (int n = 0; n < 4; ++n)
                #pragma unroll
                for (int r = 0; r < 4; ++r)
                    Ts[(m0 + quad*4 + r)*TPAD + n*16 + q16] = f2b(acc[n][r]);
            __syncthreads();
            int j    = t >> 2;
            int kseg = t & 3;
            unsigned pk[8];
            #pragma unroll
            for (int i = 0; i < 8; ++i) {
                unsigned lo = Ts[(kseg*16 + 2*i    )*TPAD + j];
                unsigned hi = Ts[(kseg*16 + 2*i + 1)*TPAD + j];
                pk[i] = lo | (hi << 16);
            }
            int bb_ = r0 >> 11;
            int k0g = r0 & (L_ - 1);
            unsigned short* dst = Vt + (size_t)(bb_*D_ + e0 + j)*L_ + k0g + kseg*16;
            *(uint4*)dst       = make_uint4(pk[0], pk[1], pk[2], pk[3]);
            *((uint4*)dst + 1) = make_uint4(pk[4], pk[5], pk[6], pk[7]);
        }
    }

    if (type < 2) {
        float* norm = (type == 0) ? qn : kn;
        #pragma unroll
        for (int r = 0; r < 4; ++r) {
            float v = p4[r];
            v += __shfl_xor(v, 1, 16);
            v += __shfl_xor(v, 2, 16);
            v += __shfl_xor(v, 4, 16);
            v += __shfl_xor(v, 8, 16);
            if (q16 == 0) norm[r0 + m0 + quad*4 + r] = v;
        }
    }
}

// ---- staging (DMA to LDS, XOR-swizzled global src), 128-thread blocks ----
__device__ __forceinline__ void stage_K(const unsigned short* Kb, unsigned short* ks,
                                        int bk, int k0, int w, int lane) {
    #pragma unroll
    for (int p = 0; p < 8; ++p) {
        int slot = p*128 + w*64 + lane;
        int row  = slot >> 5;
        int blk  = slot & 31;
        gl16(Kb + (size_t)(bk + k0 + row)*D_ + ((blk ^ (row & 15))*8),
             ks + (size_t)(p*128 + w*64)*8);
    }
}
__device__ __forceinline__ void stage_V(const unsigned short* Vt, unsigned short* vs,
                                        int bD, int k0, int w, int lane) {
    #pragma unroll
    for (int p = 0; p < 8; ++p) {
        int slot = p*128 + w*64 + lane;
        int d    = slot >> 2;
        int blk  = slot & 3;
        gl16(Vt + (size_t)(bD + d)*L_ + k0 + ((blk ^ ((d >> 1) & 3))*8),
             vs + (size_t)(p*128 + w*64)*8);
    }
}

// -------- K2: 32x32-MFMA fused pass (single transcendental pass) --------
// grid (32 qb, 16 b) = 512 blocks, 128 threads = 2 waves; wave owns 32 q rows
// as one 32x32 MFMA tile per kt. Per kt: QK (16 mfma) -> E=exp(exp(-dist))
// -> rowsum (regs) -> Es roundtrip -> PV (16 mfma) -> stream E bf16.
// 32x32 layouts: A/B: m|n=lane&31, k=(lane>>5)*8+j. C/D: col=lane&31,
// row=(reg&3)+8*(reg>>2)+4*(lane>>5).
__global__ __launch_bounds__(128) void attnpv_kernel(
    const unsigned short* __restrict__ Qb, const unsigned short* __restrict__ Kb,
    const unsigned short* __restrict__ Vt,
    const float* __restrict__ qn, const float* __restrict__ kn,
    const unsigned char* __restrict__ mask,
    unsigned short* __restrict__ Eb,
    float* __restrict__ rowsum, float* __restrict__ att_out)
{
    __shared__ unsigned short Ks[2][32*256];   // 16 KB each
    __shared__ unsigned short Vs[2][256*32];   // 16 KB each
    __shared__ unsigned short Es[2][32*EPAD];  // per-wave E tile (2.5 KB each)

    const int t  = threadIdx.x;
    const int q0 = blockIdx.x * 64;
    const int b  = blockIdx.y;
    const int bk = b * L_;
    const int bD = b * D_;
    const int w    = t >> 6;        // wave 0/1
    const int lane = t & 63;
    const int col  = lane & 31;     // k-col (QK) / d-col (PV) / q-row (A)
    const int h    = lane >> 5;     // k-group

    const int qrow = bk + q0 + w*32;

    // Q A-frags: frag c covers k = c*16 + h*8 .. +8, row = col
    s8v qa[16];
    #pragma unroll
    for (int c = 0; c < 16; ++c)
        qa[c] = *(const s8v*)(Qb + (size_t)(qrow + col)*D_ + c*16 + h*8);

    // q-norms for this lane's 16 C-rows
    float qnr[16];
    #pragma unroll
    for (int reg = 0; reg < 16; ++reg)
        qnr[reg] = qn[qrow + (reg & 3) + 8*(reg >> 2) + 4*h];

    // E-export addressing: lane -> (row = lane>>1, half-row = lane&1)
    unsigned short* ebase = Eb + (size_t)(qrow + (lane >> 1))*L_ + (lane & 1)*16;
    const unsigned short* esrc = &Es[w][(lane >> 1)*EPAD + (lane & 1)*16];

    float rs[16];
    #pragma unroll
    for (int reg = 0; reg < 16; ++reg) rs[reg] = 0.f;
    f16v O[8];
    #pragma unroll
    for (int n = 0; n < 8; ++n)
        #pragma unroll
        for (int reg = 0; reg < 16; ++reg) O[n][reg] = 0.f;

    stage_K(Kb, Ks[0], bk, 0, w, lane);
    stage_V(Vt, Vs[0], bD, 0, w, lane);
    for (int kt = 0; kt < 64; ++kt) {
        const int k0 = kt * 32;
        const int cur = kt & 1;
        __syncthreads();                       // Ks/Vs[cur] ready; prev free
        if (kt < 63) {
            stage_K(Kb, Ks[cur ^ 1], bk, k0 + 32, w, lane);
            stage_V(Vt, Vs[cur ^ 1], bD, k0 + 32, w, lane);
        }

        const float kc = kn[bk + k0 + col];
        const int   mk = mask[bk + k0 + col];

        // QK^T: one 32x32 tile, K-chain of 16
        f16v s;
        #pragma unroll
        for (int reg = 0; reg < 16; ++reg) s[reg] = 0.f;
        #pragma unroll
        for (int c = 0; c < 16; ++c) {
            // B[k=c*16+h*8+j][n=col] = Ks[row=col][d=c*16+h*8..], swizzled
            s8v bb = *(const s8v*)(Ks[cur] + col*256 + (((2*c + h) ^ (col & 15))*8));
            s = __builtin_amdgcn_mfma_f32_32x32x16_bf16(qa[c], bb, s, 0, 0, 0);
        }

        #pragma unroll
        for (int reg = 0; reg < 16; ++reg) {
            float d2 = qnr[reg] + kc - 2.0f * s[reg];
            float dist = __builtin_amdgcn_sqrtf(fmaxf(d2, 0.f));
            float E = mk ? 0.f : __expf(__expf(-dist));
            rs[reg] += E;
            Es[w][((reg & 3) + 8*(reg >> 2) + 4*h)*EPAD + col] = f2b(E);
        }

        // PV: A = Es (32q x 32k), B = Vs[d][k]; 8 d-tiles x 2 K-steps
        s8v af0 = *(const s8v*)(&Es[w][col*EPAD + h*8]);
        s8v af1 = *(const s8v*)(&Es[w][col*EPAD + 16 + h*8]);
        #pragma unroll
        for (int n = 0; n < 8; ++n) {
            int d  = n*32 + col;
            int sw = (d >> 1) & 3;
            s8v vb0 = *(const s8v*)(Vs[cur] + d*32 + ((h ^ sw)*8));
            s8v vb1 = *(const s8v*)(Vs[cur] + d*32 + (((2 + h) ^ sw)*8));
            O[n] = __builtin_amdgcn_mfma_f32_32x32x16_bf16(af0, vb0, O[n], 0, 0, 0);
            O[n] = __builtin_amdgcn_mfma_f32_32x32x16_bf16(af1, vb1, O[n], 0, 0, 0);
        }

        // stream E tile (row-major bf16) for the normalize pass
        *(s8v*)(ebase + k0)     = *(const s8v*)esrc;
        *(s8v*)(ebase + k0 + 8) = *(const s8v*)(esrc + 8);
    }

    // rowsum: reduce across the 32 col-lanes (same rows per h-group)
    float inv[16];
    #pragma unroll
    for (int reg = 0; reg < 16; ++reg) {
        float v = rs[reg];
        v += __shfl_xor(v, 1, 32);
        v += __shfl_xor(v, 2, 32);
        v += __shfl_xor(v, 4, 32);
        v += __shfl_xor(v, 8, 32);
        v += __shfl_xor(v, 16, 32);
        if (col == 0) rowsum[qrow + (reg & 3) + 8*(reg >> 2) + 4*h] = v;
        inv[reg] = 1.0f / v;
    }

    #pragma unroll
    for (int n = 0; n < 8; ++n)
        #pragma unroll
        for (int reg = 0; reg < 16; ++reg)
            att_out[(size_t)(qrow + (reg & 3) + 8*(reg >> 2) + 4*h)*D_ + n*32 + col]
                = O[n][reg] * inv[reg];
}

// -------- K3: attn = E * (1/rowsum), elementwise, HBM-bound --------
__global__ __launch_bounds__(256) void norm_kernel(
    const unsigned short* __restrict__ Eb,
    const float* __restrict__ rowsum,
    float* __restrict__ attn_out)
{
    const int row = blockIdx.x;
    const int t   = threadIdx.x;
    const float inv = 1.0f / rowsum[row];
    const size_t base = (size_t)row * L_ + t*8;

    s8v e = *(const s8v*)(Eb + base);
    float4 o0, o1;
    o0.x = __builtin_bit_cast(float, ((unsigned)(unsigned short)e[0]) << 16) * inv;
    o0.y = __builtin_bit_cast(float, ((unsigned)(unsigned short)e[1]) << 16) * inv;
    o0.z = __builtin_bit_cast(float, ((unsigned)(unsigned short)e[2]) << 16) * inv;
    o0.w = __builtin_bit_cast(float, ((unsigned)(unsigned short)e[3]) << 16) * inv;
    o1.x = __builtin_bit_cast(float, ((unsigned)(unsigned short)e[4]) << 16) * inv;
    o1.y = __builtin_bit_cast(float, ((unsigned)(unsigned short)e[5]) << 16) * inv;
    o1.z = __builtin_bit_cast(float, ((unsigned)(unsigned short)e[6]) << 16) * inv;
    o1.w = __builtin_bit_cast(float, ((unsigned)(unsigned short)e[7]) << 16) * inv;
    *(float4*)(attn_out + base)     = o0;
    *(float4*)(attn_out + base + 4) = o1;
}

extern "C" void kernel_launch(void* const* d_in, const int* in_sizes, int n_in,
                              void* d_out, int out_size, void* d_ws, size_t ws_size,
                              hipStream_t stream) {
    (void)in_sizes; (void)n_in; (void)out_size; (void)ws_size;
    const float* x  = (const float*)d_in[0];
    const float* y  = (const float*)d_in[1];
    const unsigned char* mask = (const unsigned char*)d_in[2];
    const float* Wq = (const float*)d_in[3];
    const float* Wk = (const float*)d_in[4];
    const float* Wv = (const float*)d_in[5];

    // ws: Qb | Kb | Vt (bf16) | qn | kn | rowsum (fp32) | Eb (bf16, 134 MB)
    char* ws = (char*)d_ws;
    unsigned short* Qb = (unsigned short*)ws;
    unsigned short* Kb = Qb + (size_t)NROW * D_;
    unsigned short* Vt = Kb + (size_t)NROW * D_;
    float* qn     = (float*)(ws + 3 * (size_t)NROW * D_ * 2);
    float* kn     = qn + NROW;
    float* rowsum = kn + NROW;
    unsigned short* Eb = (unsigned short*)(rowsum + NROW);

    float* att_out = (float*)d_out;                       // [B, LQ, D]
    float* attn    = att_out + (size_t)NROW * D_;         // [B, LQ, LK]

    qkv_kernel<<<dim3(512, 3), 256, 0, stream>>>(x, y, Wq, Wk, Wv,
                                                 Qb, Kb, Vt, qn, kn);
    attnpv_kernel<<<dim3(32, 16), 128, 0, stream>>>(Qb, Kb, Vt, qn, kn, mask,
                                                    Eb, rowsum, att_out);
    norm_kernel<<<dim3(NROW), 256, 0, stream>>>(Eb, rowsum, attn);
}